// Round 5
// baseline (776.329 us; speedup 1.0000x reference)
//
#include <hip/hip_runtime.h>

#define BB 32
#define DD 4096
#define HH 32
#define KVHH 8
#define HDD 128
#define SS 2048
#define NCOL1 6144
#define NCOL2 4096

// ---------------------------------------------------------------------------
// Kernel 1: split-K partial GEMV for q/k/v projections.
// grid = (24 col-blocks, nsplits), 256 threads.
// Thread owns one output column, 32 batch accumulators. Weight reads are
// lane-coalesced; x reads are wave-uniform float4 (dwordx4 broadcast).
// ---------------------------------------------------------------------------
__global__ __launch_bounds__(256) void qkv_part_kernel(
    const float* __restrict__ x, const float* __restrict__ wq,
    const float* __restrict__ wk, const float* __restrict__ wv,
    float* __restrict__ part, int chunk)
{
    const int tid = threadIdx.x;
    const int cb  = blockIdx.x;
    const int s   = blockIdx.y;

    const float* W; int ld; int outcol; int wcol;
    if (cb < 16)      { W = wq; ld = 4096; wcol = cb * 256 + tid;        outcol = wcol; }
    else if (cb < 20) { W = wk; ld = 1024; wcol = (cb - 16) * 256 + tid; outcol = 4096 + wcol; }
    else              { W = wv; ld = 1024; wcol = (cb - 20) * 256 + tid; outcol = 5120 + wcol; }

    float acc[BB];
#pragma unroll
    for (int b = 0; b < BB; ++b) acc[b] = 0.0f;

    const int d0 = s * chunk;
    const float* wp = W + (size_t)d0 * ld + wcol;

    for (int d4 = 0; d4 < (chunk >> 2); ++d4) {
        const int d = d0 + d4 * 4;
        const float w0 = wp[0];
        const float w1 = wp[ld];
        const float w2 = wp[2 * (size_t)ld];
        const float w3 = wp[3 * (size_t)ld];
        wp += 4 * (size_t)ld;
#pragma unroll
        for (int b = 0; b < BB; ++b) {
            const float4 xv = *reinterpret_cast<const float4*>(x + (size_t)b * DD + d);
            acc[b] = fmaf(xv.x, w0, fmaf(xv.y, w1, fmaf(xv.z, w2, fmaf(xv.w, w3, acc[b]))));
        }
    }

#pragma unroll
    for (int b = 0; b < BB; ++b)
        part[((size_t)(s * BB + b)) * NCOL1 + outcol] = acc[b];
}

// ---------------------------------------------------------------------------
// Kernel 2: reduce split-K partials, apply RoPE to q/k, write k/v into caches,
// store rotated q to workspace. One thread per (even,odd) pair.
// ---------------------------------------------------------------------------
__global__ __launch_bounds__(256) void reduce_rope_kernel(
    const float* __restrict__ part, const float* __restrict__ fcos,
    const float* __restrict__ fsin, float* __restrict__ kc,
    float* __restrict__ vc, float* __restrict__ qout,
    const int* __restrict__ spp, int nsplits)
{
    const int p  = blockIdx.x * 256 + threadIdx.x;   // 0..98303
    const int b  = p / 3072;
    const int cp = p - b * 3072;
    const int col = cp * 2;

    float re = 0.0f, im = 0.0f;
    for (int s = 0; s < nsplits; ++s) {
        const float* base = part + ((size_t)(s * BB + b)) * NCOL1 + col;
        re += base[0];
        im += base[1];
    }

    const int sp = *spp;

    if (col < 4096) {                       // q path: rope, store to ws
        const int i = (col & 127) >> 1;
        const float fc = fcos[sp * 64 + i];
        const float fs = fsin[sp * 64 + i];
        qout[(size_t)b * 4096 + col]     = re * fc - im * fs;
        qout[(size_t)b * 4096 + col + 1] = re * fs + im * fc;
    } else if (col < 5120) {                // k path: rope, write cache
        const int c = col - 4096;
        const int i = (c & 127) >> 1;
        const float fc = fcos[sp * 64 + i];
        const float fs = fsin[sp * 64 + i];
        const size_t idx = (((size_t)b * SS + sp) * KVHH + (c >> 7)) * HDD + (c & 127);
        kc[idx]     = re * fc - im * fs;
        kc[idx + 1] = re * fs + im * fc;
    } else {                                // v path: write cache
        const int c = col - 5120;
        const size_t idx = (((size_t)b * SS + sp) * KVHH + (c >> 7)) * HDD + (c & 127);
        vc[idx]     = re;
        vc[idx + 1] = im;
    }
}

// ---------------------------------------------------------------------------
// Kernel 3: GQA attention decode. One block per (b, kv_head) = 256 blocks,
// 1024 threads (16 waves -> 4 waves/SIMD for latency hiding).
// QK^T: lane-per-position, q broadcast from LDS (no cross-lane reduction).
// Softmax: wave w handles head w.
// PV: 32 slots of 32 lanes; slot handles position t; lane holds 4 dims.
// ---------------------------------------------------------------------------
__global__ __launch_bounds__(1024) void attn_kernel(
    const float* __restrict__ qin, const float* __restrict__ kc,
    const float* __restrict__ vc, float* __restrict__ attn_out,
    const int* __restrict__ spp)
{
    __shared__ float s_q[4][HDD];          // 2 KB: q for the 4 heads of this group
    __shared__ float s_sc[4][1026];        // 16.4 KB: scores -> exp weights
    __shared__ float s_pv[16][4][HDD];     // 32 KB: per-wave PV partials
    __shared__ float s_inv[4];

    const int tid = threadIdx.x;
    const int b   = blockIdx.x >> 3;
    const int g   = blockIdx.x & 7;        // kv head
    const int P   = *spp + 1;              // valid positions 0..start_pos
    const float scale = 0.08838834764831845f;   // 1/sqrt(128)

    // ---- stage q ----
    if (tid < 512) {
        const int h = tid >> 7, d = tid & 127;
        s_q[h][d] = qin[((size_t)(b * HH + g * 4 + h)) * HDD + d];
    }
    __syncthreads();

    // ---- QK^T: lane-per-position ----
    const float* kb = kc + (size_t)b * SS * (KVHH * HDD) + (size_t)g * HDD;
    for (int t = tid; t < P; t += 1024) {
        const float* kp = kb + (size_t)t * (KVHH * HDD);
        float s0 = 0.0f, s1 = 0.0f, s2 = 0.0f, s3 = 0.0f;
#pragma unroll 4
        for (int j = 0; j < 32; ++j) {
            const float4 kv = *reinterpret_cast<const float4*>(kp + 4 * j);
            const float4 q0 = *reinterpret_cast<const float4*>(&s_q[0][4 * j]);
            const float4 q1 = *reinterpret_cast<const float4*>(&s_q[1][4 * j]);
            const float4 q2 = *reinterpret_cast<const float4*>(&s_q[2][4 * j]);
            const float4 q3 = *reinterpret_cast<const float4*>(&s_q[3][4 * j]);
            s0 += q0.x * kv.x + q0.y * kv.y + q0.z * kv.z + q0.w * kv.w;
            s1 += q1.x * kv.x + q1.y * kv.y + q1.z * kv.z + q1.w * kv.w;
            s2 += q2.x * kv.x + q2.y * kv.y + q2.z * kv.z + q2.w * kv.w;
            s3 += q3.x * kv.x + q3.y * kv.y + q3.z * kv.z + q3.w * kv.w;
        }
        s_sc[0][t] = s0 * scale;
        s_sc[1][t] = s1 * scale;
        s_sc[2][t] = s2 * scale;
        s_sc[3][t] = s3 * scale;
    }
    __syncthreads();

    // ---- softmax: wave w handles head w (waves 0..3 active) ----
    if (tid < 256) {
        const int wv_ = tid >> 6;
        const int ln  = tid & 63;
        float m = -1e30f;
        for (int t = ln; t < P; t += 64) m = fmaxf(m, s_sc[wv_][t]);
#pragma unroll
        for (int mm = 32; mm; mm >>= 1) m = fmaxf(m, __shfl_xor(m, mm));
        float sum = 0.0f;
        for (int t = ln; t < P; t += 64) {
            const float e = __expf(s_sc[wv_][t] - m);
            s_sc[wv_][t] = e;
            sum += e;
        }
#pragma unroll
        for (int mm = 32; mm; mm >>= 1) sum += __shfl_xor(sum, mm);
        if (ln == 0) s_inv[wv_] = 1.0f / sum;
    }
    __syncthreads();

    // ---- PV: 32 slots of 32 lanes ----
    const int slot = tid >> 5;
    const int sl   = tid & 31;
    float acc[4][4];
#pragma unroll
    for (int hh = 0; hh < 4; ++hh)
#pragma unroll
        for (int j = 0; j < 4; ++j) acc[hh][j] = 0.0f;

    const float* vbase = vc + (size_t)b * SS * (KVHH * HDD) + (size_t)g * HDD + 4 * sl;
    for (int t = slot; t < P; t += 32) {
        const float4 vv = *reinterpret_cast<const float4*>(vbase + (size_t)t * (KVHH * HDD));
#pragma unroll
        for (int hh = 0; hh < 4; ++hh) {
            const float w = s_sc[hh][t];
            acc[hh][0] += w * vv.x;
            acc[hh][1] += w * vv.y;
            acc[hh][2] += w * vv.z;
            acc[hh][3] += w * vv.w;
        }
    }

    // combine the wave's two slots (lane <-> lane+32), then write per-wave partial
#pragma unroll
    for (int hh = 0; hh < 4; ++hh)
#pragma unroll
        for (int j = 0; j < 4; ++j)
            acc[hh][j] += __shfl_xor(acc[hh][j], 32);

    if ((tid & 32) == 0) {
        const int wv_ = tid >> 6;
#pragma unroll
        for (int hh = 0; hh < 4; ++hh) {
            float* dst = &s_pv[wv_][hh][4 * sl];
            dst[0] = acc[hh][0]; dst[1] = acc[hh][1];
            dst[2] = acc[hh][2]; dst[3] = acc[hh][3];
        }
    }
    __syncthreads();

    // ---- cross-wave reduce + normalize + store ----
    if (tid < 512) {
        const int h = tid >> 7, d = tid & 127;
        float r = 0.0f;
#pragma unroll
        for (int w2 = 0; w2 < 16; ++w2) r += s_pv[w2][h][d];
        attn_out[((size_t)(b * HH + g * 4 + h)) * HDD + d] = r * s_inv[h];
    }
}

// ---------------------------------------------------------------------------
// Kernel 4: split-K partial GEMV for output projection (attn @ wo).
// grid = (16 col-blocks, nsplits), 256 threads.
// ---------------------------------------------------------------------------
__global__ __launch_bounds__(256) void o_part_kernel(
    const float* __restrict__ x2, const float* __restrict__ wo,
    float* __restrict__ part, int chunk)
{
    const int tid = threadIdx.x;
    const int col = blockIdx.x * 256 + tid;
    const int s   = blockIdx.y;

    float acc[BB];
#pragma unroll
    for (int b = 0; b < BB; ++b) acc[b] = 0.0f;

    const int d0 = s * chunk;
    const float* wp = wo + (size_t)d0 * 4096 + col;

    for (int d4 = 0; d4 < (chunk >> 2); ++d4) {
        const int d = d0 + d4 * 4;
        const float w0 = wp[0];
        const float w1 = wp[4096];
        const float w2 = wp[8192];
        const float w3 = wp[12288];
        wp += 16384;
#pragma unroll
        for (int b = 0; b < BB; ++b) {
            const float4 xv = *reinterpret_cast<const float4*>(x2 + (size_t)b * 4096 + d);
            acc[b] = fmaf(xv.x, w0, fmaf(xv.y, w1, fmaf(xv.z, w2, fmaf(xv.w, w3, acc[b]))));
        }
    }

#pragma unroll
    for (int b = 0; b < BB; ++b)
        part[((size_t)(s * BB + b)) * NCOL2 + col] = acc[b];
}

// ---------------------------------------------------------------------------
// Kernel 5: reduce output-projection partials -> d_out.
// ---------------------------------------------------------------------------
__global__ __launch_bounds__(256) void reduce_o_kernel(
    const float* __restrict__ part, float* __restrict__ out, int nsplits)
{
    const int i   = blockIdx.x * 256 + threadIdx.x;   // 0..131071
    const int b   = i >> 12;
    const int col = i & 4095;
    float r = 0.0f;
    for (int s = 0; s < nsplits; ++s)
        r += part[((size_t)(s * BB + b)) * NCOL2 + col];
    out[i] = r;
}

// ---------------------------------------------------------------------------
extern "C" void kernel_launch(void* const* d_in, const int* in_sizes, int n_in,
                              void* d_out, int out_size, void* d_ws, size_t ws_size,
                              hipStream_t stream)
{
    const float* x    = (const float*)d_in[0];
    const float* wq   = (const float*)d_in[1];
    const float* wk   = (const float*)d_in[2];
    const float* wv   = (const float*)d_in[3];
    const float* wo   = (const float*)d_in[4];
    float*       kc   = (float*)d_in[5];    // mutated: new token written at start_pos
    float*       vc   = (float*)d_in[6];    // (harness restores inputs each launch)
    const float* fcos = (const float*)d_in[7];
    const float* fsin = (const float*)d_in[8];
    // d_in[9] = mask: unused (equivalent to iterating t in [0, start_pos])
    const int*   spp  = (const int*)d_in[10];

    float* out = (float*)d_out;
    float* ws  = (float*)d_ws;

    // Choose split-K factor from the actual workspace size (ws_size is fixed
    // across calls -> identical work every launch; graph-capture safe).
    // ws layout (floats):
    //   [0, nsplits*32*6144)  : qkv split-K partials, later reused for
    //                           o-proj partials (nsplits*32*4096 <= that)
    //   [+0, +131072)         : rotated q (32 x 32 x 128)
    //   [+131072, +262144)    : attention output (32 x 32 x 128)
    const size_t ws_floats = ws_size / 4;
    int nsplits = 16;
    while (nsplits > 1 &&
           (size_t)nsplits * BB * NCOL1 + 262144 > ws_floats)
        nsplits >>= 1;
    const int chunk = DD / nsplits;

    float* part1 = ws;
    float* qout  = ws + (size_t)nsplits * BB * NCOL1;
    float* attn  = qout + 131072;
    float* part2 = ws;   // alias: part1 fully consumed before this is written

    qkv_part_kernel   <<<dim3(24, nsplits), 256, 0, stream>>>(x, wq, wk, wv, part1, chunk);
    reduce_rope_kernel<<<384, 256, 0, stream>>>(part1, fcos, fsin, kc, vc, qout, spp, nsplits);
    attn_kernel       <<<256, 1024, 0, stream>>>(qout, kc, vc, attn, spp);
    o_part_kernel     <<<dim3(16, nsplits), 256, 0, stream>>>(attn, wo, part2, chunk);
    reduce_o_kernel   <<<512, 256, 0, stream>>>(part2, out, nsplits);
}

// Round 7
// 718.033 us; speedup vs baseline: 1.0812x; 1.0812x over previous
//
#include <hip/hip_runtime.h>

#define BB 32
#define DD 4096
#define HH 32
#define KVHH 8
#define HDD 128
#define SS 2048
#define NCOL1 6144
#define NCOL2 4096
#define MAXSPLITS 32

// ---------------------------------------------------------------------------
// Kernel 1: split-K partial GEMV for q/k/v projections.
// grid = (24 col-blocks, nsplits=32), 256 threads -> 768 blocks = 3 blocks/CU.
// Thread owns one output column, 32 batch accumulators. Weight reads are
// lane-coalesced; 8 independent weight-row loads in flight per iteration.
// x reads are wave-uniform float4 (scalar-cache broadcast).
// ---------------------------------------------------------------------------
__global__ __launch_bounds__(256) void qkv_part_kernel(
    const float* __restrict__ x, const float* __restrict__ wq,
    const float* __restrict__ wk, const float* __restrict__ wv,
    float* __restrict__ part, int chunk)
{
    const int tid = threadIdx.x;
    const int cb  = blockIdx.x;
    const int s   = blockIdx.y;

    const float* W; int ld; int outcol; int wcol;
    if (cb < 16)      { W = wq; ld = 4096; wcol = cb * 256 + tid;        outcol = wcol; }
    else if (cb < 20) { W = wk; ld = 1024; wcol = (cb - 16) * 256 + tid; outcol = 4096 + wcol; }
    else              { W = wv; ld = 1024; wcol = (cb - 20) * 256 + tid; outcol = 5120 + wcol; }

    float acc[BB];
#pragma unroll
    for (int b = 0; b < BB; ++b) acc[b] = 0.0f;

    const int d0 = s * chunk;
    const float* wp = W + (size_t)d0 * ld + wcol;

    for (int d8 = 0; d8 < (chunk >> 3); ++d8) {
        const int d = d0 + d8 * 8;
        // 8 independent weight-row loads issued together (ILP for HBM latency)
        const float w0 = wp[0];
        const float w1 = wp[1 * (size_t)ld];
        const float w2 = wp[2 * (size_t)ld];
        const float w3 = wp[3 * (size_t)ld];
        const float w4 = wp[4 * (size_t)ld];
        const float w5 = wp[5 * (size_t)ld];
        const float w6 = wp[6 * (size_t)ld];
        const float w7 = wp[7 * (size_t)ld];
        wp += 8 * (size_t)ld;
#pragma unroll
        for (int b = 0; b < BB; ++b) {
            const float4 xa = *reinterpret_cast<const float4*>(x + (size_t)b * DD + d);
            const float4 xb = *reinterpret_cast<const float4*>(x + (size_t)b * DD + d + 4);
            float a = acc[b];
            a = fmaf(xa.x, w0, a); a = fmaf(xa.y, w1, a);
            a = fmaf(xa.z, w2, a); a = fmaf(xa.w, w3, a);
            a = fmaf(xb.x, w4, a); a = fmaf(xb.y, w5, a);
            a = fmaf(xb.z, w6, a); a = fmaf(xb.w, w7, a);
            acc[b] = a;
        }
    }

#pragma unroll
    for (int b = 0; b < BB; ++b)
        part[((size_t)(s * BB + b)) * NCOL1 + outcol] = acc[b];
}

// ---------------------------------------------------------------------------
// Kernel 2: reduce split-K partials, apply RoPE to q/k, write k/v into caches,
// store rotated q to workspace. One thread per (even,odd) pair.
// ---------------------------------------------------------------------------
__global__ __launch_bounds__(256) void reduce_rope_kernel(
    const float* __restrict__ part, const float* __restrict__ fcos,
    const float* __restrict__ fsin, float* __restrict__ kc,
    float* __restrict__ vc, float* __restrict__ qout,
    const int* __restrict__ spp, int nsplits)
{
    const int p  = blockIdx.x * 256 + threadIdx.x;   // 0..98303
    const int b  = p / 3072;
    const int cp = p - b * 3072;
    const int col = cp * 2;

    float re = 0.0f, im = 0.0f;
    for (int s = 0; s < nsplits; ++s) {
        const float* base = part + ((size_t)(s * BB + b)) * NCOL1 + col;
        re += base[0];
        im += base[1];
    }

    const int sp = *spp;

    if (col < 4096) {                       // q path: rope, store to ws
        const int i = (col & 127) >> 1;
        const float fc = fcos[sp * 64 + i];
        const float fs = fsin[sp * 64 + i];
        qout[(size_t)b * 4096 + col]     = re * fc - im * fs;
        qout[(size_t)b * 4096 + col + 1] = re * fs + im * fc;
    } else if (col < 5120) {                // k path: rope, write cache
        const int c = col - 4096;
        const int i = (c & 127) >> 1;
        const float fc = fcos[sp * 64 + i];
        const float fs = fsin[sp * 64 + i];
        const size_t idx = (((size_t)b * SS + sp) * KVHH + (c >> 7)) * HDD + (c & 127);
        kc[idx]     = re * fc - im * fs;
        kc[idx + 1] = re * fs + im * fc;
    } else {                                // v path: write cache
        const int c = col - 5120;
        const size_t idx = (((size_t)b * SS + sp) * KVHH + (c >> 7)) * HDD + (c & 127);
        vc[idx]     = re;
        vc[idx + 1] = im;
    }
}

// ---------------------------------------------------------------------------
// Kernel 3: GQA attention decode. One block per (b, kv_head) = 256 blocks,
// 1024 threads (16 waves -> 4 waves/SIMD for latency hiding).
// QK^T: lane-per-position, q broadcast from LDS (no cross-lane reduction).
// Softmax: wave w handles head w.
// PV: 32 slots of 32 lanes; slot handles position t; lane holds 4 dims.
// ---------------------------------------------------------------------------
__global__ __launch_bounds__(1024) void attn_kernel(
    const float* __restrict__ qin, const float* __restrict__ kc,
    const float* __restrict__ vc, float* __restrict__ attn_out,
    const int* __restrict__ spp)
{
    __shared__ float s_q[4][HDD];          // 2 KB: q for the 4 heads of this group
    __shared__ float s_sc[4][1026];        // 16.4 KB: scores -> exp weights
    __shared__ float s_pv[16][4][HDD];     // 32 KB: per-wave PV partials
    __shared__ float s_inv[4];

    const int tid = threadIdx.x;
    const int b   = blockIdx.x >> 3;
    const int g   = blockIdx.x & 7;        // kv head
    const int P   = *spp + 1;              // valid positions 0..start_pos
    const float scale = 0.08838834764831845f;   // 1/sqrt(128)

    // ---- stage q ----
    if (tid < 512) {
        const int h = tid >> 7, d = tid & 127;
        s_q[h][d] = qin[((size_t)(b * HH + g * 4 + h)) * HDD + d];
    }
    __syncthreads();

    // ---- QK^T: lane-per-position ----
    const float* kb = kc + (size_t)b * SS * (KVHH * HDD) + (size_t)g * HDD;
    for (int t = tid; t < P; t += 1024) {
        const float* kp = kb + (size_t)t * (KVHH * HDD);
        float s0 = 0.0f, s1 = 0.0f, s2 = 0.0f, s3 = 0.0f;
#pragma unroll 4
        for (int j = 0; j < 32; ++j) {
            const float4 kv = *reinterpret_cast<const float4*>(kp + 4 * j);
            const float4 q0 = *reinterpret_cast<const float4*>(&s_q[0][4 * j]);
            const float4 q1 = *reinterpret_cast<const float4*>(&s_q[1][4 * j]);
            const float4 q2 = *reinterpret_cast<const float4*>(&s_q[2][4 * j]);
            const float4 q3 = *reinterpret_cast<const float4*>(&s_q[3][4 * j]);
            s0 += q0.x * kv.x + q0.y * kv.y + q0.z * kv.z + q0.w * kv.w;
            s1 += q1.x * kv.x + q1.y * kv.y + q1.z * kv.z + q1.w * kv.w;
            s2 += q2.x * kv.x + q2.y * kv.y + q2.z * kv.z + q2.w * kv.w;
            s3 += q3.x * kv.x + q3.y * kv.y + q3.z * kv.z + q3.w * kv.w;
        }
        s_sc[0][t] = s0 * scale;
        s_sc[1][t] = s1 * scale;
        s_sc[2][t] = s2 * scale;
        s_sc[3][t] = s3 * scale;
    }
    __syncthreads();

    // ---- softmax: wave w handles head w (waves 0..3 active) ----
    if (tid < 256) {
        const int wv_ = tid >> 6;
        const int ln  = tid & 63;
        float m = -1e30f;
        for (int t = ln; t < P; t += 64) m = fmaxf(m, s_sc[wv_][t]);
#pragma unroll
        for (int mm = 32; mm; mm >>= 1) m = fmaxf(m, __shfl_xor(m, mm));
        float sum = 0.0f;
        for (int t = ln; t < P; t += 64) {
            const float e = __expf(s_sc[wv_][t] - m);
            s_sc[wv_][t] = e;
            sum += e;
        }
#pragma unroll
        for (int mm = 32; mm; mm >>= 1) sum += __shfl_xor(sum, mm);
        if (ln == 0) s_inv[wv_] = 1.0f / sum;
    }
    __syncthreads();

    // ---- PV: 32 slots of 32 lanes ----
    const int slot = tid >> 5;
    const int sl   = tid & 31;
    float acc[4][4];
#pragma unroll
    for (int hh = 0; hh < 4; ++hh)
#pragma unroll
        for (int j = 0; j < 4; ++j) acc[hh][j] = 0.0f;

    const float* vbase = vc + (size_t)b * SS * (KVHH * HDD) + (size_t)g * HDD + 4 * sl;
    for (int t = slot; t < P; t += 32) {
        const float4 vv = *reinterpret_cast<const float4*>(vbase + (size_t)t * (KVHH * HDD));
#pragma unroll
        for (int hh = 0; hh < 4; ++hh) {
            const float w = s_sc[hh][t];
            acc[hh][0] += w * vv.x;
            acc[hh][1] += w * vv.y;
            acc[hh][2] += w * vv.z;
            acc[hh][3] += w * vv.w;
        }
    }

    // combine the wave's two slots (lane <-> lane+32), then write per-wave partial
#pragma unroll
    for (int hh = 0; hh < 4; ++hh)
#pragma unroll
        for (int j = 0; j < 4; ++j)
            acc[hh][j] += __shfl_xor(acc[hh][j], 32);

    if ((tid & 32) == 0) {
        const int wv_ = tid >> 6;
#pragma unroll
        for (int hh = 0; hh < 4; ++hh) {
            float* dst = &s_pv[wv_][hh][4 * sl];
            dst[0] = acc[hh][0]; dst[1] = acc[hh][1];
            dst[2] = acc[hh][2]; dst[3] = acc[hh][3];
        }
    }
    __syncthreads();

    // ---- cross-wave reduce + normalize + store ----
    if (tid < 512) {
        const int h = tid >> 7, d = tid & 127;
        float r = 0.0f;
#pragma unroll
        for (int w2 = 0; w2 < 16; ++w2) r += s_pv[w2][h][d];
        attn_out[((size_t)(b * HH + g * 4 + h)) * HDD + d] = r * s_inv[h];
    }
}

// ---------------------------------------------------------------------------
// Kernel 4: split-K partial GEMV for output projection (attn @ wo).
// grid = (16 col-blocks, nsplits=32), 256 threads -> 512 blocks = 2/CU.
// ---------------------------------------------------------------------------
__global__ __launch_bounds__(256) void o_part_kernel(
    const float* __restrict__ x2, const float* __restrict__ wo,
    float* __restrict__ part, int chunk)
{
    const int tid = threadIdx.x;
    const int col = blockIdx.x * 256 + tid;
    const int s   = blockIdx.y;

    float acc[BB];
#pragma unroll
    for (int b = 0; b < BB; ++b) acc[b] = 0.0f;

    const int d0 = s * chunk;
    const float* wp = wo + (size_t)d0 * 4096 + col;

    for (int d8 = 0; d8 < (chunk >> 3); ++d8) {
        const int d = d0 + d8 * 8;
        const float w0 = wp[0];
        const float w1 = wp[4096];
        const float w2 = wp[8192];
        const float w3 = wp[12288];
        const float w4 = wp[16384];
        const float w5 = wp[20480];
        const float w6 = wp[24576];
        const float w7 = wp[28672];
        wp += 32768;
#pragma unroll
        for (int b = 0; b < BB; ++b) {
            const float4 xa = *reinterpret_cast<const float4*>(x2 + (size_t)b * 4096 + d);
            const float4 xb = *reinterpret_cast<const float4*>(x2 + (size_t)b * 4096 + d + 4);
            float a = acc[b];
            a = fmaf(xa.x, w0, a); a = fmaf(xa.y, w1, a);
            a = fmaf(xa.z, w2, a); a = fmaf(xa.w, w3, a);
            a = fmaf(xb.x, w4, a); a = fmaf(xb.y, w5, a);
            a = fmaf(xb.z, w6, a); a = fmaf(xb.w, w7, a);
            acc[b] = a;
        }
    }

#pragma unroll
    for (int b = 0; b < BB; ++b)
        part[((size_t)(s * BB + b)) * NCOL2 + col] = acc[b];
}

// ---------------------------------------------------------------------------
// Kernel 5: reduce output-projection partials -> d_out.
// ---------------------------------------------------------------------------
__global__ __launch_bounds__(256) void reduce_o_kernel(
    const float* __restrict__ part, float* __restrict__ out, int nsplits)
{
    const int i   = blockIdx.x * 256 + threadIdx.x;   // 0..131071
    const int b   = i >> 12;
    const int col = i & 4095;
    float r = 0.0f;
    for (int s = 0; s < nsplits; ++s)
        r += part[((size_t)(s * BB + b)) * NCOL2 + col];
    out[i] = r;
}

// ---------------------------------------------------------------------------
extern "C" void kernel_launch(void* const* d_in, const int* in_sizes, int n_in,
                              void* d_out, int out_size, void* d_ws, size_t ws_size,
                              hipStream_t stream)
{
    const float* x    = (const float*)d_in[0];
    const float* wq   = (const float*)d_in[1];
    const float* wk   = (const float*)d_in[2];
    const float* wv   = (const float*)d_in[3];
    const float* wo   = (const float*)d_in[4];
    float*       kc   = (float*)d_in[5];    // mutated: new token written at start_pos
    float*       vc   = (float*)d_in[6];    // (harness restores inputs each launch)
    const float* fcos = (const float*)d_in[7];
    const float* fsin = (const float*)d_in[8];
    // d_in[9] = mask: unused (equivalent to iterating t in [0, start_pos])
    const int*   spp  = (const int*)d_in[10];

    float* out = (float*)d_out;
    float* ws  = (float*)d_ws;

    // Choose split-K factor from the actual workspace size (ws_size is fixed
    // across calls -> identical work every launch; graph-capture safe).
    // ws layout (floats):
    //   [0, nsplits*32*6144)  : qkv split-K partials, later reused for
    //                           o-proj partials (nsplits*32*4096 <= that)
    //   [+0, +131072)         : rotated q (32 x 32 x 128)
    //   [+131072, +262144)    : attention output (32 x 32 x 128)
    const size_t ws_floats = ws_size / 4;
    int nsplits = MAXSPLITS;
    while (nsplits > 1 &&
           (size_t)nsplits * BB * NCOL1 + 262144 > ws_floats)
        nsplits >>= 1;
    const int chunk = DD / nsplits;

    float* part1 = ws;
    float* qout  = ws + (size_t)nsplits * BB * NCOL1;
    float* attn  = qout + 131072;
    float* part2 = ws;   // alias: part1 fully consumed before this is written

    qkv_part_kernel   <<<dim3(24, nsplits), 256, 0, stream>>>(x, wq, wk, wv, part1, chunk);
    reduce_rope_kernel<<<384, 256, 0, stream>>>(part1, fcos, fsin, kc, vc, qout, spp, nsplits);
    attn_kernel       <<<256, 1024, 0, stream>>>(qout, kc, vc, attn, spp);
    o_part_kernel     <<<dim3(16, nsplits), 256, 0, stream>>>(attn, wo, part2, chunk);
    reduce_o_kernel   <<<512, 256, 0, stream>>>(part2, out, nsplits);
}